// Round 18
// baseline (291.378 us; speedup 1.0000x reference)
//
#include <hip/hip_runtime.h>

#define MM 4096
#define NN 4096
#define KK 4096
#define NT (KK / 64)

typedef __attribute__((ext_vector_type(8))) _Float16 f16x8;
typedef __attribute__((ext_vector_type(2))) _Float16 f16x2;
typedef __attribute__((ext_vector_type(4))) float f32x4;
typedef __attribute__((ext_vector_type(4))) int i32x4;

__device__ __forceinline__ f16x2 pk16(float a, float b) {
  return __builtin_bit_cast(f16x2, __builtin_amdgcn_cvt_pkrtz(a, b));
}

__device__ __forceinline__ void gload_lds16(const void* g, void* l) {
  __builtin_amdgcn_global_load_lds(
      (const __attribute__((address_space(1))) unsigned int*)g,
      (__attribute__((address_space(3))) unsigned int*)l, 16, 0, 0);
}

// ================= pre-pass 1: A fp32 -> fp16 =================
__global__ __launch_bounds__(256) void cvt_a(const float* __restrict__ A,
                                             _Float16* __restrict__ Ah) {
  const size_t i = ((size_t)blockIdx.x * 256 + threadIdx.x) * 8;
  f32x4 v0 = *(const f32x4*)(A + i);
  f32x4 v1 = *(const f32x4*)(A + i + 4);
  union { f16x2 h2[4]; f16x8 v; } u;
  u.h2[0] = pk16(v0[0], v0[1]);
  u.h2[1] = pk16(v0[2], v0[3]);
  u.h2[2] = pk16(v1[0], v1[1]);
  u.h2[3] = pk16(v1[2], v1[3]);
  *(f16x8*)(Ah + i) = u.v;
}

// ====== pre-pass 2: dequant Q[k][n] -> W^T[n][k] fp16 (64x64 LDS transpose) ======
__global__ __launch_bounds__(256) void deq_wt(const int* __restrict__ Q,
                                              const float* __restrict__ S,
                                              const float* __restrict__ Z,
                                              _Float16* __restrict__ WT) {
  __shared__ _Float16 T[64][72];
  const int tid = threadIdx.x;
  const int n0 = ((int)blockIdx.x & 63) * 64;
  const int k0 = ((int)blockIdx.x >> 6) * 64;
  const int g = k0 >> 7;

  const int c4 = (tid & 15) * 4;
  f32x4 s4 = *(const f32x4*)(S + (size_t)g * NN + n0 + c4);
  f32x4 z4 = *(const f32x4*)(Z + (size_t)g * NN + n0 + c4);
#pragma unroll
  for (int p = 0; p < 4; ++p) {
    const int r = (tid >> 4) + p * 16;
    i32x4 q = *(const i32x4*)(Q + (size_t)(k0 + r) * NN + n0 + c4);
#pragma unroll
    for (int j = 0; j < 4; ++j)
      T[c4 + j][r] = (_Float16)(((float)q[j] - z4[j]) * s4[j]);
  }
  __syncthreads();
  const int n = tid >> 2;
  const int kc = (tid & 3) * 16;
  f16x8 w0 = *(const f16x8*)&T[n][kc];
  f16x8 w1 = *(const f16x8*)&T[n][kc + 8];
  _Float16* dst = WT + (size_t)(n0 + n) * KK + k0 + kc;
  *(f16x8*)dst = w0;
  *(f16x8*)(dst + 8) = w1;
}

// ==== main GEMM: 256x256, 8 waves; A direct global->reg (L2), B via LDS ====
// Serial-sum model (R11..R17, exact): phase time = LDS-pipe time + MFMA time.
// This round REMOVES the A term from the LDS pipe: A fragments are tracked
// global loads issued ONE K-TILE AHEAD (L2-hot panel; VMEM pipe is idle).
// LDS holds only B (64KB, dbuf): per K-tile LDS ops = 64 reads + 32 DMA.
// A-reg WAR: loads for t+1 are placed AFTER the last MFMA use of that half's
// regs; compiler inserts the vmcnt wait before next tile's first use, and by
// FIFO order that wait also drains the previous B-stage (ledger-sound).
// B ledger: lgkm(0) before b2 -> all waves' B-reads done -> restage Bs[buf];
// vmcnt(20) at tail = everything older than this tile's 20 VMEM ops drained.

#define DSR(DST, ADDR, IMM)                                              \
  asm volatile("ds_read_b128 %0, %1 offset:%2"                           \
               : "=v"(DST) : "v"(ADDR), "i"(IMM))

#define OFFB(BUF, G, E) (((BUF) * 2 + (G)) * 16384 + (E) * 2048)

#define READ_BSET(BUF, G)                                                \
  DSR(bF[G][0][0], bAddr0, OFFB(BUF, G, 0));                             \
  DSR(bF[G][0][1], bAddr0, OFFB(BUF, G, 1));                             \
  DSR(bF[G][1][0], bAddr1, OFFB(BUF, G, 0));                             \
  DSR(bF[G][1][1], bAddr1, OFFB(BUF, G, 1))

#define STAGE_B(BUF, G, T)                                               \
  { const _Float16* src_ = WT + b_srow[G] + (size_t)(T) * 64;            \
    char* dst_ = (char*)&Bs[BUF][G][0] + wid * 1024;                     \
    gload_lds16(src_, dst_);                                             \
    gload_lds16(src_ + (size_t)64 * KK, dst_ + 8192); }

// A fragment loads for K-tile T into aF[H] (8 tracked global_load_dwordx4)
#define LOAD_A_H(H, T)                                                   \
  { const _Float16* ap_ = a_base + (size_t)(H) * 128 * KK + (size_t)(T) * 64; \
    aF[H][0][0] = *(const f16x8*)(ap_ + (size_t)0 * 16 * KK);            \
    aF[H][0][1] = *(const f16x8*)(ap_ + (size_t)1 * 16 * KK);            \
    aF[H][0][2] = *(const f16x8*)(ap_ + (size_t)2 * 16 * KK);            \
    aF[H][0][3] = *(const f16x8*)(ap_ + (size_t)3 * 16 * KK);            \
    aF[H][1][0] = *(const f16x8*)(ap_ + (size_t)0 * 16 * KK + 32);       \
    aF[H][1][1] = *(const f16x8*)(ap_ + (size_t)1 * 16 * KK + 32);       \
    aF[H][1][2] = *(const f16x8*)(ap_ + (size_t)2 * 16 * KK + 32);       \
    aF[H][1][3] = *(const f16x8*)(ap_ + (size_t)3 * 16 * KK + 32);       \
  }

#define MMAQ(H, G)                                                       \
  _Pragma("unroll") for (int ks = 0; ks < 2; ++ks)                       \
  _Pragma("unroll") for (int f = 0; f < 4; ++f)                          \
  _Pragma("unroll") for (int e = 0; e < 2; ++e)                          \
    acc[H][f][G][e] = __builtin_amdgcn_mfma_f32_16x16x32_f16(            \
        aF[H][ks][f], bF[G][ks][e], acc[H][f][G][e], 0, 0, 0);

// MEGA(BUF, TNXT, TSTG): consume tile in Bs[BUF] + aF regs; prefetch A(TNXT);
// restage Bs[BUF] <- TSTG.
#define MEGA(BUF, TNXT, TSTG)                                            \
  READ_BSET(BUF, 0);                                                     \
  READ_BSET(BUF, 1);                                                     \
  asm volatile("s_waitcnt lgkmcnt(4)" ::: "memory");                     \
  __builtin_amdgcn_sched_barrier(0);                                     \
  __builtin_amdgcn_s_setprio(1);                                         \
  MMAQ(0, 0);                                                            \
  __builtin_amdgcn_s_setprio(0);                                         \
  asm volatile("s_waitcnt lgkmcnt(0)" ::: "memory");                     \
  __builtin_amdgcn_sched_barrier(0);                                     \
  __builtin_amdgcn_s_setprio(1);                                         \
  MMAQ(0, 1);                                                            \
  __builtin_amdgcn_s_setprio(0);                                         \
  LOAD_A_H(0, TNXT);                                                     \
  __builtin_amdgcn_sched_barrier(0);                                     \
  __builtin_amdgcn_s_barrier(); /* b2: all waves' B-reads of BUF done */ \
  STAGE_B(BUF, 0, TSTG);                                                 \
  STAGE_B(BUF, 1, TSTG);                                                 \
  __builtin_amdgcn_s_setprio(1);                                         \
  MMAQ(1, 1);                                                            \
  MMAQ(1, 0);                                                            \
  __builtin_amdgcn_s_setprio(0);                                         \
  LOAD_A_H(1, TNXT);                                                     \
  asm volatile("s_waitcnt vmcnt(20)" ::: "memory");                      \
  __builtin_amdgcn_sched_barrier(0);                                     \
  __builtin_amdgcn_s_barrier(); /* b1: other buf's stage visible */

__global__ __launch_bounds__(512, 2) void gemm256(const _Float16* __restrict__ Ah,
                                                  const _Float16* __restrict__ WT,
                                                  float* __restrict__ C) {
  __shared__ __align__(16) _Float16 Bs[2][2][128 * 64];  // [buf][g][r][k], 64KB

  const int tid = threadIdx.x;
  const int lane = tid & 63;
  const int wid = tid >> 6;

  // bijective XCD swizzle (nwg=256 % 8 == 0); m fast-varying -> B L2-hot
  const int nwg = (int)gridDim.x;
  const int bid0 = (int)blockIdx.x;
  const int wg = (bid0 & 7) * (nwg >> 3) + (bid0 >> 3);
  const int m0 = (wg & 15) * 256;
  const int n0 = (wg >> 4) * 256;

  // B staging: wave stages 8 rows/pass, 2 passes per half-tile; pre-swizzled src
  const int st_row = wid * 8 + (lane >> 3);
  const int st_k = ((lane & 7) ^ (lane >> 3)) * 8;
  size_t b_srow[2];
#pragma unroll
  for (int g = 0; g < 2; ++g)
    b_srow[g] = (size_t)(n0 + g * 128 + st_row) * KK + st_k;

  // compute-side addressing
  const int wm = wid >> 2, wn = wid & 3;
  const int lr = lane & 15, lg = lane >> 4;
  int koffx[2];
#pragma unroll
  for (int ks = 0; ks < 2; ++ks)
    koffx[ks] = ((ks * 32 + lg * 8) * 2) ^ ((lr & 7) << 4);

  const unsigned bsBase =
      (unsigned)(size_t)(__attribute__((address_space(3))) _Float16*)&Bs[0][0][0];
  const unsigned bAddr0 = bsBase + wn * 4096 + lr * 128 + koffx[0];
  const unsigned bAddr1 = bsBase + wn * 4096 + lr * 128 + koffx[1];

  // A direct-from-global base: lane (lr,lg) -> row m0+wm*64+lr (+f*16+h*128),
  // k = t*64 + ks*32 + lg*8 (canonical fragment layout)
  const _Float16* a_base = Ah + (size_t)(m0 + wm * 64 + lr) * KK + lg * 8;

  f32x4 acc[2][4][2][2];
#pragma unroll
  for (int h = 0; h < 2; ++h)
#pragma unroll
    for (int f = 0; f < 4; ++f)
#pragma unroll
      for (int g = 0; g < 2; ++g)
#pragma unroll
        for (int e = 0; e < 2; ++e) acc[h][f][g][e] = (f32x4){0.f, 0.f, 0.f, 0.f};

  f16x8 aF[2][2][4];  // [h][ks][f] — tile-t operands, reloaded for t+1 in-tile
  f16x8 bF[2][2][2];  // [g][ks][e]

  // ---- prologue: stage Bs buf0<-tile0, buf1<-tile1; load A(tile0) ----
  STAGE_B(0, 0, 0);
  STAGE_B(0, 1, 0);
  STAGE_B(1, 0, 1);
  STAGE_B(1, 1, 1);
  LOAD_A_H(0, 0);
  LOAD_A_H(1, 0);
  asm volatile("s_waitcnt vmcnt(16)" ::: "memory");  // drain 8 B-stage DMAs
  __builtin_amdgcn_sched_barrier(0);
  __builtin_amdgcn_s_barrier();

  // ---- main loop: 2 K-tiles per iteration ----
  for (int i = 0; i < NT / 2; ++i) {
    const int t1 = 2 * i + 1;
    const int t2 = (2 * i + 2) & (NT - 1);  // wrap: harmless reload/restage
    const int t3 = (2 * i + 3) & (NT - 1);
    MEGA(0, t1, t2);  // consume tile 2i (Bs0 + aF), prefetch A(t1), stage Bs0<-t2
    MEGA(1, t2, t3);  // consume tile t1, prefetch A(t2), stage Bs1<-t3
  }

  // ---- epilogue: C/D col=lane&15, row=(lane>>4)*4+reg ----
#pragma unroll
  for (int h = 0; h < 2; ++h)
#pragma unroll
    for (int f = 0; f < 4; ++f) {
      const int row0 = m0 + h * 128 + wm * 64 + f * 16 + lg * 4;
#pragma unroll
      for (int g = 0; g < 2; ++g)
#pragma unroll
        for (int e = 0; e < 2; ++e) {
          const int col = n0 + g * 128 + wn * 32 + e * 16 + lr;
#pragma unroll
          for (int r = 0; r < 4; ++r)
            C[(size_t)(row0 + r) * NN + col] = acc[h][f][g][e][r];
        }
    }
}

// ================= fallback: Round-5 fused kernel (proven) =================
__global__ __launch_bounds__(256, 2) void wq_gemm(
    const float* __restrict__ A, const int* __restrict__ Q,
    const float* __restrict__ S, const float* __restrict__ Z,
    float* __restrict__ C) {
  __shared__ __align__(16) _Float16 AsBuf[2][128 * 64];
  __shared__ __align__(16) _Float16 BsBuf[2][128 * 64];

  const int tid = threadIdx.x;
  const int lane = tid & 63;
  const int wid = tid >> 6;

  const int nwg = (int)gridDim.x;
  const int bid0 = (int)blockIdx.x;
  const int wg = (bid0 & 7) * (nwg >> 3) + (bid0 >> 3);
  const int m0 = (wg & 31) * 128;
  const int n0 = (wg >> 5) * 128;

  const int a_m = tid >> 3;
  const int a_k = (tid & 7) * 8;
  const float* a_src = A + (size_t)(m0 + a_m) * KK + a_k;
  const int a_woff = a_m * 128 + ((a_k * 2) ^ ((a_m & 7) << 4));

  const int n_loc = tid & 127;
  const int kk0 = (tid >> 7) * 32;
  const int* q_src = Q + (size_t)kk0 * NN + (n0 + n_loc);
  const float* s_src = S + (n0 + n_loc);
  const float* z_src = Z + (n0 + n_loc);
  int bw_off[4];
#pragma unroll
  for (int j = 0; j < 4; ++j)
    bw_off[j] = n_loc * 128 + (((kk0 + j * 8) * 2) ^ ((n_loc & 7) << 4));

  const int wm = wid >> 1, wn = wid & 1;
  const int lr = lane & 15, lg = lane >> 4;
  const int rx = (lr & 7) << 4;
  int a_row[4], b_row[4], koffx[2];
#pragma unroll
  for (int f = 0; f < 4; ++f) {
    a_row[f] = (wm * 64 + f * 16 + lr) * 128;
    b_row[f] = (wn * 64 + f * 16 + lr) * 128;
  }
#pragma unroll
  for (int ks = 0; ks < 2; ++ks)
    koffx[ks] = ((ks * 32 + lg * 8) * 2) ^ rx;

  f32x4 acc[4][4];
#pragma unroll
  for (int i = 0; i < 4; ++i)
#pragma unroll
    for (int j = 0; j < 4; ++j) acc[i][j] = (f32x4){0.f, 0.f, 0.f, 0.f};

  f32x4 av[8];
  int qv[32];
  float sf, bfv;

  auto stage_load = [&](int t) {
    const float* ap = a_src + (size_t)t * 64;
#pragma unroll
    for (int p = 0; p < 4; ++p) {
      av[p * 2] = *(const f32x4*)(ap + (size_t)p * 32 * KK);
      av[p * 2 + 1] = *(const f32x4*)(ap + (size_t)p * 32 * KK + 4);
    }
    const int* qp = q_src + (size_t)t * 64 * NN;
#pragma unroll
    for (int i = 0; i < 32; ++i) qv[i] = qp[(size_t)i * NN];
    const int g = t >> 1;
    sf = s_src[(size_t)g * NN];
    bfv = -z_src[(size_t)g * NN] * sf;
  };

  auto stage_write = [&](int c) {
    char* as = (char*)&AsBuf[c][0];
#pragma unroll
    for (int p = 0; p < 4; ++p) {
      union { f16x2 h2[4]; f16x8 v; } u;
      f32x4 v0 = av[p * 2], v1 = av[p * 2 + 1];
      u.h2[0] = pk16(v0[0], v0[1]);
      u.h2[1] = pk16(v0[2], v0[3]);
      u.h2[2] = pk16(v1[0], v1[1]);
      u.h2[3] = pk16(v1[2], v1[3]);
      *(f16x8*)(as + a_woff + p * 4096) = u.v;
    }
    char* bs = (char*)&BsBuf[c][0];
#pragma unroll
    for (int j = 0; j < 4; ++j) {
      union { f16x2 h2[4]; f16x8 v; } u;
#pragma unroll
      for (int p = 0; p < 4; ++p) {
        float w0 = (float)qv[j * 8 + p * 2] * sf + bfv;
        float w1 = (float)qv[j * 8 + p * 2 + 1] * sf + bfv;
        u.h2[p] = pk16(w0, w1);
      }
      *(f16x8*)(bs + bw_off[j]) = u.v;
    }
  };

  stage_load(0);
  stage_write(0);
  __syncthreads();

  for (int t = 0; t < NT; ++t) {
    const int c = t & 1;
    if (t + 1 < NT) stage_load(t + 1);
    {
      const char* as = (const char*)&AsBuf[c][0];
      const char* bs = (const char*)&BsBuf[c][0];
#pragma unroll
      for (int ks = 0; ks < 2; ++ks) {
        f16x8 a4[4], b4[4];
#pragma unroll
        for (int f = 0; f < 4; ++f) {
          a4[f] = *(const f16x8*)(as + (a_row[f] + koffx[ks]));
          b4[f] = *(const f16x8*)(bs + (b_row[f] + koffx[ks]));
        }
#pragma unroll
        for (int i = 0; i < 4; ++i)
#pragma unroll
          for (int j = 0; j < 4; ++j)
            acc[i][j] = __builtin_amdgcn_mfma_f32_16x16x32_f16(
                a4[i], b4[j], acc[i][j], 0, 0, 0);
      }
    }
    if (t + 1 < NT) stage_write(c ^ 1);
    __syncthreads();
  }

#pragma unroll
  for (int i = 0; i < 4; ++i) {
    const int row0 = m0 + wm * 64 + i * 16 + lg * 4;
#pragma unroll
    for (int j = 0; j < 4; ++j) {
      const int col = n0 + wn * 64 + j * 16 + lr;
#pragma unroll
      for (int r = 0; r < 4; ++r)
        C[(size_t)(row0 + r) * NN + col] = acc[i][j][r];
    }
  }
}

extern "C" void kernel_launch(void* const* d_in, const int* in_sizes, int n_in,
                              void* d_out, int out_size, void* d_ws, size_t ws_size,
                              hipStream_t stream) {
  const float* A = (const float*)d_in[0];
  const int* Q = (const int*)d_in[1];
  const float* S = (const float*)d_in[2];
  const float* Z = (const float*)d_in[3];
  float* C = (float*)d_out;

  const size_t needA = (size_t)MM * KK * sizeof(_Float16);
  const size_t needW = (size_t)KK * NN * sizeof(_Float16);
  if (ws_size >= needA + needW) {
    _Float16* Ah = (_Float16*)d_ws;
    _Float16* WT = (_Float16*)((char*)d_ws + needA);
    cvt_a<<<dim3(MM * KK / (8 * 256)), dim3(256), 0, stream>>>(A, Ah);
    deq_wt<<<dim3((KK / 64) * (NN / 64)), dim3(256), 0, stream>>>(Q, S, Z, WT);
    gemm256<<<dim3((MM / 256) * (NN / 256)), dim3(512), 0, stream>>>(Ah, WT, C);
  } else {
    wq_gemm<<<dim3((MM / 128) * (NN / 128)), dim3(256), 0, stream>>>(A, Q, S, Z, C);
  }
}

// Round 19
// 173.409 us; speedup vs baseline: 1.6803x; 1.6803x over previous
//
#include <hip/hip_runtime.h>

#define MM 4096
#define NN 4096
#define KK 4096
#define NT (KK / 64)

typedef __attribute__((ext_vector_type(8))) _Float16 f16x8;
typedef __attribute__((ext_vector_type(2))) _Float16 f16x2;
typedef __attribute__((ext_vector_type(4))) float f32x4;
typedef __attribute__((ext_vector_type(4))) int i32x4;

__device__ __forceinline__ f16x2 pk16(float a, float b) {
  return __builtin_bit_cast(f16x2, __builtin_amdgcn_cvt_pkrtz(a, b));
}

__device__ __forceinline__ void gload_lds16(const void* g, void* l) {
  __builtin_amdgcn_global_load_lds(
      (const __attribute__((address_space(1))) unsigned int*)g,
      (__attribute__((address_space(3))) unsigned int*)l, 16, 0, 0);
}

// ================= pre-pass 1: A fp32 -> fp16 =================
__global__ __launch_bounds__(256) void cvt_a(const float* __restrict__ A,
                                             _Float16* __restrict__ Ah) {
  const size_t i = ((size_t)blockIdx.x * 256 + threadIdx.x) * 8;
  f32x4 v0 = *(const f32x4*)(A + i);
  f32x4 v1 = *(const f32x4*)(A + i + 4);
  union { f16x2 h2[4]; f16x8 v; } u;
  u.h2[0] = pk16(v0[0], v0[1]);
  u.h2[1] = pk16(v0[2], v0[3]);
  u.h2[2] = pk16(v1[0], v1[1]);
  u.h2[3] = pk16(v1[2], v1[3]);
  *(f16x8*)(Ah + i) = u.v;
}

// ====== pre-pass 2: dequant Q[k][n] -> W^T[n][k] fp16 (64x64 LDS transpose) ======
__global__ __launch_bounds__(256) void deq_wt(const int* __restrict__ Q,
                                              const float* __restrict__ S,
                                              const float* __restrict__ Z,
                                              _Float16* __restrict__ WT) {
  __shared__ _Float16 T[64][72];
  const int tid = threadIdx.x;
  const int n0 = ((int)blockIdx.x & 63) * 64;
  const int k0 = ((int)blockIdx.x >> 6) * 64;
  const int g = k0 >> 7;

  const int c4 = (tid & 15) * 4;
  f32x4 s4 = *(const f32x4*)(S + (size_t)g * NN + n0 + c4);
  f32x4 z4 = *(const f32x4*)(Z + (size_t)g * NN + n0 + c4);
#pragma unroll
  for (int p = 0; p < 4; ++p) {
    const int r = (tid >> 4) + p * 16;
    i32x4 q = *(const i32x4*)(Q + (size_t)(k0 + r) * NN + n0 + c4);
#pragma unroll
    for (int j = 0; j < 4; ++j)
      T[c4 + j][r] = (_Float16)(((float)q[j] - z4[j]) * s4[j]);
  }
  __syncthreads();
  const int n = tid >> 2;
  const int kc = (tid & 3) * 16;
  f16x8 w0 = *(const f16x8*)&T[n][kc];
  f16x8 w1 = *(const f16x8*)&T[n][kc + 8];
  _Float16* dst = WT + (size_t)(n0 + n) * KK + k0 + kc;
  *(f16x8*)dst = w0;
  *(f16x8*)(dst + 8) = w1;
}

// ==== main GEMM: 128x128 tile, 4 waves, 2 BLOCKS/CU (cross-block overlap) ====
// In-block scheduling cannot overlap LDS reads with MFMA (R11-R17: barrier-
// locked waves advance in lockstep; phase = LDS + MFMA serial). Co-resident
// INDEPENDENT blocks overlap for free (m114/m97). This kernel: 64KB LDS ->
// 2 blocks/CU; one barrier per K-tile; stage issued at TOP of tile (~800cyc
// before its vmcnt(0) at the tail -> drain nearly free, unlike R8's mid-tile
// drain); asm untracked ds_reads + counted lgkmcnt(8/0) (R14/R15-proven).
// Ledger: tile t consumes buf c=t&1 (staged at tile t-1, drained by t-1's
// tail vmcnt(0)+barrier); stages buf c^1 <- tile t+1 (c^1 dead since t-1's
// lgkm(0), behind >=1 barrier). Reads of c vs DMA into c^1: disjoint buffers.

#define DSR(DST, ADDR, IMM)                                              \
  asm volatile("ds_read_b128 %0, %1 offset:%2"                           \
               : "=v"(DST) : "v"(ADDR), "i"(IMM))

#define OFFT(BUF, F) ((BUF) * 16384 + (F) * 2048)

#define READ_TILE(BUF)                                                   \
  DSR(aF[0][0], aAddr0, OFFT(BUF, 0));                                   \
  DSR(aF[0][1], aAddr0, OFFT(BUF, 1));                                   \
  DSR(aF[0][2], aAddr0, OFFT(BUF, 2));                                   \
  DSR(aF[0][3], aAddr0, OFFT(BUF, 3));                                   \
  DSR(bF[0][0], bAddr0, OFFT(BUF, 0));                                   \
  DSR(bF[0][1], bAddr0, OFFT(BUF, 1));                                   \
  DSR(bF[0][2], bAddr0, OFFT(BUF, 2));                                   \
  DSR(bF[0][3], bAddr0, OFFT(BUF, 3));                                   \
  DSR(aF[1][0], aAddr1, OFFT(BUF, 0));                                   \
  DSR(aF[1][1], aAddr1, OFFT(BUF, 1));                                   \
  DSR(aF[1][2], aAddr1, OFFT(BUF, 2));                                   \
  DSR(aF[1][3], aAddr1, OFFT(BUF, 3));                                   \
  DSR(bF[1][0], bAddr1, OFFT(BUF, 0));                                   \
  DSR(bF[1][1], bAddr1, OFFT(BUF, 1));                                   \
  DSR(bF[1][2], bAddr1, OFFT(BUF, 2));                                   \
  DSR(bF[1][3], bAddr1, OFFT(BUF, 3))

#define STAGE_A(BUF, T)                                                  \
  { const _Float16* src_ = Ah + a_srow + (size_t)(T) * 64;               \
    char* dst_ = (char*)&As[BUF][0] + wid * 1024;                        \
    gload_lds16(src_, dst_);                                             \
    gload_lds16(src_ + (size_t)32 * KK, dst_ + 4096);                    \
    gload_lds16(src_ + (size_t)64 * KK, dst_ + 8192);                    \
    gload_lds16(src_ + (size_t)96 * KK, dst_ + 12288); }

#define STAGE_B(BUF, T)                                                  \
  { const _Float16* src_ = WT + b_srow + (size_t)(T) * 64;               \
    char* dst_ = (char*)&Bs[BUF][0] + wid * 1024;                        \
    gload_lds16(src_, dst_);                                             \
    gload_lds16(src_ + (size_t)32 * KK, dst_ + 4096);                    \
    gload_lds16(src_ + (size_t)64 * KK, dst_ + 8192);                    \
    gload_lds16(src_ + (size_t)96 * KK, dst_ + 12288); }

#define MMAQ(KS)                                                         \
  _Pragma("unroll") for (int f = 0; f < 4; ++f)                          \
  _Pragma("unroll") for (int e = 0; e < 4; ++e)                          \
    acc[f][e] = __builtin_amdgcn_mfma_f32_16x16x32_f16(                  \
        aF[KS][f], bF[KS][e], acc[f][e], 0, 0, 0);

#define MEGA(C, TN)                                                      \
  STAGE_A(C ^ 1, TN);                                                    \
  STAGE_B(C ^ 1, TN);                                                    \
  READ_TILE(C);                                                          \
  asm volatile("s_waitcnt lgkmcnt(8)" ::: "memory");                     \
  __builtin_amdgcn_sched_barrier(0);                                     \
  __builtin_amdgcn_s_setprio(1);                                         \
  MMAQ(0);                                                               \
  __builtin_amdgcn_s_setprio(0);                                         \
  asm volatile("s_waitcnt lgkmcnt(0)" ::: "memory");                     \
  __builtin_amdgcn_sched_barrier(0);                                     \
  __builtin_amdgcn_s_setprio(1);                                         \
  MMAQ(1);                                                               \
  __builtin_amdgcn_s_setprio(0);                                         \
  asm volatile("s_waitcnt vmcnt(0)" ::: "memory");                       \
  __builtin_amdgcn_sched_barrier(0);                                     \
  __builtin_amdgcn_s_barrier();

__global__ __launch_bounds__(256, 2) void gemm128d(const _Float16* __restrict__ Ah,
                                                   const _Float16* __restrict__ WT,
                                                   float* __restrict__ C) {
  __shared__ __align__(16) _Float16 As[2][128 * 64];  // [buf][r][k], 16KB each
  __shared__ __align__(16) _Float16 Bs[2][128 * 64];

  const int tid = threadIdx.x;
  const int lane = tid & 63;
  const int wid = tid >> 6;

  // bijective XCD swizzle (nwg=1024 % 8 == 0); m fast-varying -> B panel reuse
  const int nwg = (int)gridDim.x;
  const int bid0 = (int)blockIdx.x;
  const int wg = (bid0 & 7) * (nwg >> 3) + (bid0 >> 3);
  const int m0 = (wg & 31) * 128;
  const int n0 = (wg >> 5) * 128;

  // staging: 4 waves x 8 rows per pass, 4 passes (128 rows); pre-swizzled src
  const int st_row = wid * 8 + (lane >> 3);
  const int st_k = ((lane & 7) ^ (lane >> 3)) * 8;
  const size_t a_srow = (size_t)(m0 + st_row) * KK + st_k;
  const size_t b_srow = (size_t)(n0 + st_row) * KK + st_k;

  // compute-side fragment addressing (16x16x32), 64x64 per wave
  const int wm = wid >> 1, wn = wid & 1;
  const int lr = lane & 15, lg = lane >> 4;
  int koffx[2];
#pragma unroll
  for (int ks = 0; ks < 2; ++ks)
    koffx[ks] = ((ks * 32 + lg * 8) * 2) ^ ((lr & 7) << 4);

  const unsigned asBase =
      (unsigned)(size_t)(__attribute__((address_space(3))) _Float16*)&As[0][0];
  const unsigned bsBase =
      (unsigned)(size_t)(__attribute__((address_space(3))) _Float16*)&Bs[0][0];
  const unsigned aAddr0 = asBase + wm * 8192 + lr * 128 + koffx[0];
  const unsigned aAddr1 = asBase + wm * 8192 + lr * 128 + koffx[1];
  const unsigned bAddr0 = bsBase + wn * 8192 + lr * 128 + koffx[0];
  const unsigned bAddr1 = bsBase + wn * 8192 + lr * 128 + koffx[1];

  f32x4 acc[4][4];
#pragma unroll
  for (int f = 0; f < 4; ++f)
#pragma unroll
    for (int e = 0; e < 4; ++e) acc[f][e] = (f32x4){0.f, 0.f, 0.f, 0.f};

  f16x8 aF[2][4], bF[2][4];

  // ---- prologue: stage tile 0 -> buf0 ----
  STAGE_A(0, 0);
  STAGE_B(0, 0);
  asm volatile("s_waitcnt vmcnt(0)" ::: "memory");
  __builtin_amdgcn_sched_barrier(0);
  __builtin_amdgcn_s_barrier();

  // ---- main loop: one single-barrier mega-phase per K-tile ----
  for (int i = 0; i < NT / 2; ++i) {
    const int t1 = 2 * i + 1;
    const int t2 = (2 * i + 2) & (NT - 1);  // wrap on last iter (harmless)
    MEGA(0, t1);
    MEGA(1, t2);
  }

  // ---- epilogue: C/D col=lane&15, row=(lane>>4)*4+reg ----
#pragma unroll
  for (int f = 0; f < 4; ++f) {
    const int row0 = m0 + wm * 64 + f * 16 + lg * 4;
#pragma unroll
    for (int e = 0; e < 4; ++e) {
      const int col = n0 + wn * 64 + e * 16 + lr;
#pragma unroll
      for (int r = 0; r < 4; ++r)
        C[(size_t)(row0 + r) * NN + col] = acc[f][e][r];
    }
  }
}

// ================= fallback: Round-5 fused kernel (proven) =================
__global__ __launch_bounds__(256, 2) void wq_gemm(
    const float* __restrict__ A, const int* __restrict__ Q,
    const float* __restrict__ S, const float* __restrict__ Z,
    float* __restrict__ C) {
  __shared__ __align__(16) _Float16 AsBuf[2][128 * 64];
  __shared__ __align__(16) _Float16 BsBuf[2][128 * 64];

  const int tid = threadIdx.x;
  const int lane = tid & 63;
  const int wid = tid >> 6;

  const int nwg = (int)gridDim.x;
  const int bid0 = (int)blockIdx.x;
  const int wg = (bid0 & 7) * (nwg >> 3) + (bid0 >> 3);
  const int m0 = (wg & 31) * 128;
  const int n0 = (wg >> 5) * 128;

  const int a_m = tid >> 3;
  const int a_k = (tid & 7) * 8;
  const float* a_src = A + (size_t)(m0 + a_m) * KK + a_k;
  const int a_woff = a_m * 128 + ((a_k * 2) ^ ((a_m & 7) << 4));

  const int n_loc = tid & 127;
  const int kk0 = (tid >> 7) * 32;
  const int* q_src = Q + (size_t)kk0 * NN + (n0 + n_loc);
  const float* s_src = S + (n0 + n_loc);
  const float* z_src = Z + (n0 + n_loc);
  int bw_off[4];
#pragma unroll
  for (int j = 0; j < 4; ++j)
    bw_off[j] = n_loc * 128 + (((kk0 + j * 8) * 2) ^ ((n_loc & 7) << 4));

  const int wm = wid >> 1, wn = wid & 1;
  const int lr = lane & 15, lg = lane >> 4;
  const int rx = (lr & 7) << 4;
  int a_row[4], b_row[4], koffx[2];
#pragma unroll
  for (int f = 0; f < 4; ++f) {
    a_row[f] = (wm * 64 + f * 16 + lr) * 128;
    b_row[f] = (wn * 64 + f * 16 + lr) * 128;
  }
#pragma unroll
  for (int ks = 0; ks < 2; ++ks)
    koffx[ks] = ((ks * 32 + lg * 8) * 2) ^ rx;

  f32x4 acc[4][4];
#pragma unroll
  for (int i = 0; i < 4; ++i)
#pragma unroll
    for (int j = 0; j < 4; ++j) acc[i][j] = (f32x4){0.f, 0.f, 0.f, 0.f};

  f32x4 av[8];
  int qv[32];
  float sf, bfv;

  auto stage_load = [&](int t) {
    const float* ap = a_src + (size_t)t * 64;
#pragma unroll
    for (int p = 0; p < 4; ++p) {
      av[p * 2] = *(const f32x4*)(ap + (size_t)p * 32 * KK);
      av[p * 2 + 1] = *(const f32x4*)(ap + (size_t)p * 32 * KK + 4);
    }
    const int* qp = q_src + (size_t)t * 64 * NN;
#pragma unroll
    for (int i = 0; i < 32; ++i) qv[i] = qp[(size_t)i * NN];
    const int g = t >> 1;
    sf = s_src[(size_t)g * NN];
    bfv = -z_src[(size_t)g * NN] * sf;
  };

  auto stage_write = [&](int c) {
    char* as = (char*)&AsBuf[c][0];
#pragma unroll
    for (int p = 0; p < 4; ++p) {
      union { f16x2 h2[4]; f16x8 v; } u;
      f32x4 v0 = av[p * 2], v1 = av[p * 2 + 1];
      u.h2[0] = pk16(v0[0], v0[1]);
      u.h2[1] = pk16(v0[2], v0[3]);
      u.h2[2] = pk16(v1[0], v1[1]);
      u.h2[3] = pk16(v1[2], v1[3]);
      *(f16x8*)(as + a_woff + p * 4096) = u.v;
    }
    char* bs = (char*)&BsBuf[c][0];
#pragma unroll
    for (int j = 0; j < 4; ++j) {
      union { f16x2 h2[4]; f16x8 v; } u;
#pragma unroll
      for (int p = 0; p < 4; ++p) {
        float w0 = (float)qv[j * 8 + p * 2] * sf + bfv;
        float w1 = (float)qv[j * 8 + p * 2 + 1] * sf + bfv;
        u.h2[p] = pk16(w0, w1);
      }
      *(f16x8*)(bs + bw_off[j]) = u.v;
    }
  };

  stage_load(0);
  stage_write(0);
  __syncthreads();

  for (int t = 0; t < NT; ++t) {
    const int c = t & 1;
    if (t + 1 < NT) stage_load(t + 1);
    {
      const char* as = (const char*)&AsBuf[c][0];
      const char* bs = (const char*)&BsBuf[c][0];
#pragma unroll
      for (int ks = 0; ks < 2; ++ks) {
        f16x8 a4[4], b4[4];
#pragma unroll
        for (int f = 0; f < 4; ++f) {
          a4[f] = *(const f16x8*)(as + (a_row[f] + koffx[ks]));
          b4[f] = *(const f16x8*)(bs + (b_row[f] + koffx[ks]));
        }
#pragma unroll
        for (int i = 0; i < 4; ++i)
#pragma unroll
          for (int j = 0; j < 4; ++j)
            acc[i][j] = __builtin_amdgcn_mfma_f32_16x16x32_f16(
                a4[i], b4[j], acc[i][j], 0, 0, 0);
      }
    }
    if (t + 1 < NT) stage_write(c ^ 1);
    __syncthreads();
  }

#pragma unroll
  for (int i = 0; i < 4; ++i) {
    const int row0 = m0 + wm * 64 + i * 16 + lg * 4;
#pragma unroll
    for (int j = 0; j < 4; ++j) {
      const int col = n0 + wn * 64 + j * 16 + lr;
#pragma unroll
      for (int r = 0; r < 4; ++r)
        C[(size_t)(row0 + r) * NN + col] = acc[i][j][r];
    }
  }
}

extern "C" void kernel_launch(void* const* d_in, const int* in_sizes, int n_in,
                              void* d_out, int out_size, void* d_ws, size_t ws_size,
                              hipStream_t stream) {
  const float* A = (const float*)d_in[0];
  const int* Q = (const int*)d_in[1];
  const float* S = (const float*)d_in[2];
  const float* Z = (const float*)d_in[3];
  float* C = (float*)d_out;

  const size_t needA = (size_t)MM * KK * sizeof(_Float16);
  const size_t needW = (size_t)KK * NN * sizeof(_Float16);
  if (ws_size >= needA + needW) {
    _Float16* Ah = (_Float16*)d_ws;
    _Float16* WT = (_Float16*)((char*)d_ws + needA);
    cvt_a<<<dim3(MM * KK / (8 * 256)), dim3(256), 0, stream>>>(A, Ah);
    deq_wt<<<dim3((KK / 64) * (NN / 64)), dim3(256), 0, stream>>>(Q, S, Z, WT);
    gemm128d<<<dim3((MM / 128) * (NN / 128)), dim3(256), 0, stream>>>(Ah, WT, C);
  } else {
    wq_gemm<<<dim3((MM / 128) * (NN / 128)), dim3(256), 0, stream>>>(A, Q, S, Z, C);
  }
}

// Round 20
// 154.442 us; speedup vs baseline: 1.8866x; 1.1228x over previous
//
#include <hip/hip_runtime.h>

#define MM 4096
#define NN 4096
#define KK 4096
#define NT (KK / 64)

typedef __attribute__((ext_vector_type(8))) _Float16 f16x8;
typedef __attribute__((ext_vector_type(2))) _Float16 f16x2;
typedef __attribute__((ext_vector_type(4))) float f32x4;
typedef __attribute__((ext_vector_type(4))) int i32x4;

__device__ __forceinline__ f16x2 pk16(float a, float b) {
  return __builtin_bit_cast(f16x2, __builtin_amdgcn_cvt_pkrtz(a, b));
}

__device__ __forceinline__ void gload_lds16(const void* g, void* l) {
  __builtin_amdgcn_global_load_lds(
      (const __attribute__((address_space(1))) unsigned int*)g,
      (__attribute__((address_space(3))) unsigned int*)l, 16, 0, 0);
}

// ======== fused pre-pass: blocks [0,8192) convert A; [8192,12288) dequant W^T ========
__global__ __launch_bounds__(256) void prep(const float* __restrict__ A,
                                            _Float16* __restrict__ Ah,
                                            const int* __restrict__ Q,
                                            const float* __restrict__ S,
                                            const float* __restrict__ Z,
                                            _Float16* __restrict__ WT) {
  __shared__ _Float16 T[64][72];
  const int bid = (int)blockIdx.x;
  const int tid = threadIdx.x;

  if (bid < 8192) {
    // ---- A fp32 -> fp16 (exact: values round-trip fp16) ----
    const size_t i = ((size_t)bid * 256 + tid) * 8;
    f32x4 v0 = *(const f32x4*)(A + i);
    f32x4 v1 = *(const f32x4*)(A + i + 4);
    union { f16x2 h2[4]; f16x8 v; } u;
    u.h2[0] = pk16(v0[0], v0[1]);
    u.h2[1] = pk16(v0[2], v0[3]);
    u.h2[2] = pk16(v1[0], v1[1]);
    u.h2[3] = pk16(v1[2], v1[3]);
    *(f16x8*)(Ah + i) = u.v;
    return;
  }

  // ---- dequant Q[k][n] -> W^T[n][k] fp16 via 64x64 LDS transpose ----
  const int db = bid - 8192;
  const int n0 = (db & 63) * 64;
  const int k0 = (db >> 6) * 64;
  const int g = k0 >> 7;  // GS=128, 64|k0 -> group constant per tile

  const int c4 = (tid & 15) * 4;
  f32x4 s4 = *(const f32x4*)(S + (size_t)g * NN + n0 + c4);
  f32x4 z4 = *(const f32x4*)(Z + (size_t)g * NN + n0 + c4);
#pragma unroll
  for (int p = 0; p < 4; ++p) {
    const int r = (tid >> 4) + p * 16;
    i32x4 q = *(const i32x4*)(Q + (size_t)(k0 + r) * NN + n0 + c4);
#pragma unroll
    for (int j = 0; j < 4; ++j)
      T[c4 + j][r] = (_Float16)(((float)q[j] - z4[j]) * s4[j]);
  }
  __syncthreads();
  const int n = tid >> 2;
  const int kc = (tid & 3) * 16;
  f16x8 w0 = *(const f16x8*)&T[n][kc];
  f16x8 w1 = *(const f16x8*)&T[n][kc + 8];
  _Float16* dst = WT + (size_t)(n0 + n) * KK + k0 + kc;
  *(f16x8*)dst = w0;
  *(f16x8*)(dst + 8) = w1;
}

// ==== main GEMM (R17-proven): 256x256, 8 waves, K-tile mega-phase ====
// Per K-tile: issue ALL 24 asm ds_reads (order A0:8,B0:4,B1:4,A1:8; in-order
// return), then staged counted waits:
//   lgkm(12) -> MMA(h0,g0)16 ; lgkm(8) -> MMA(h0,g1)16 ; lgkm(0) -> b2
//   -> STAGE next-next tile (8 gload_lds) -> MMA(h1,g1)+MMA(h1,g0) 32
//   -> vmcnt(8) -> b1.
// b2 (after lgkm(0)) proves all waves' reads of this buf complete before its
// restage. vmcnt(8) at tail = the OTHER buffer's 8 stages landed; b1 publishes.

#define DSR(DST, ADDR, IMM)                                              \
  asm volatile("ds_read_b128 %0, %1 offset:%2"                           \
               : "=v"(DST) : "v"(ADDR), "i"(IMM))

#define OFFA(BUF, H, F) (((BUF) * 2 + (H)) * 16384 + (F) * 2048)
#define OFFB(BUF, G, E) (((BUF) * 2 + (G)) * 16384 + (E) * 2048)

#define READ_ASET(BUF, H)                                                \
  DSR(aF[H][0][0], aAddr0, OFFA(BUF, H, 0));                             \
  DSR(aF[H][0][1], aAddr0, OFFA(BUF, H, 1));                             \
  DSR(aF[H][0][2], aAddr0, OFFA(BUF, H, 2));                             \
  DSR(aF[H][0][3], aAddr0, OFFA(BUF, H, 3));                             \
  DSR(aF[H][1][0], aAddr1, OFFA(BUF, H, 0));                             \
  DSR(aF[H][1][1], aAddr1, OFFA(BUF, H, 1));                             \
  DSR(aF[H][1][2], aAddr1, OFFA(BUF, H, 2));                             \
  DSR(aF[H][1][3], aAddr1, OFFA(BUF, H, 3))

#define READ_BSET(BUF, G)                                                \
  DSR(bF[G][0][0], bAddr0, OFFB(BUF, G, 0));                             \
  DSR(bF[G][0][1], bAddr0, OFFB(BUF, G, 1));                             \
  DSR(bF[G][1][0], bAddr1, OFFB(BUF, G, 0));                             \
  DSR(bF[G][1][1], bAddr1, OFFB(BUF, G, 1))

#define STAGE_A(BUF, H, T)                                               \
  { const _Float16* src_ = Ah + a_srow[H] + (size_t)(T) * 64;            \
    char* dst_ = (char*)&As[BUF][H][0] + wid * 1024;                     \
    gload_lds16(src_, dst_);                                             \
    gload_lds16(src_ + (size_t)64 * KK, dst_ + 8192); }

#define STAGE_B(BUF, G, T)                                               \
  { const _Float16* src_ = WT + b_srow[G] + (size_t)(T) * 64;            \
    char* dst_ = (char*)&Bs[BUF][G][0] + wid * 1024;                     \
    gload_lds16(src_, dst_);                                             \
    gload_lds16(src_ + (size_t)64 * KK, dst_ + 8192); }

#define MMAQ(H, G)                                                       \
  _Pragma("unroll") for (int ks = 0; ks < 2; ++ks)                       \
  _Pragma("unroll") for (int f = 0; f < 4; ++f)                          \
  _Pragma("unroll") for (int e = 0; e < 2; ++e)                          \
    acc[H][f][G][e] = __builtin_amdgcn_mfma_f32_16x16x32_f16(            \
        aF[H][ks][f], bF[G][ks][e], acc[H][f][G][e], 0, 0, 0);

#define MEGA(BUF, TN)                                                    \
  READ_ASET(BUF, 0);                                                     \
  READ_BSET(BUF, 0);                                                     \
  READ_BSET(BUF, 1);                                                     \
  READ_ASET(BUF, 1);                                                     \
  asm volatile("s_waitcnt lgkmcnt(12)" ::: "memory");                    \
  __builtin_amdgcn_sched_barrier(0);                                     \
  __builtin_amdgcn_s_setprio(1);                                         \
  MMAQ(0, 0);                                                            \
  __builtin_amdgcn_s_setprio(0);                                         \
  asm volatile("s_waitcnt lgkmcnt(8)" ::: "memory");                     \
  __builtin_amdgcn_sched_barrier(0);                                     \
  __builtin_amdgcn_s_setprio(1);                                         \
  MMAQ(0, 1);                                                            \
  __builtin_amdgcn_s_setprio(0);                                         \
  asm volatile("s_waitcnt lgkmcnt(0)" ::: "memory");                     \
  __builtin_amdgcn_sched_barrier(0);                                     \
  __builtin_amdgcn_s_barrier(); /* b2: all reads of BUF complete */      \
  STAGE_A(BUF, 0, TN);                                                   \
  STAGE_A(BUF, 1, TN);                                                   \
  STAGE_B(BUF, 0, TN);                                                   \
  STAGE_B(BUF, 1, TN);                                                   \
  __builtin_amdgcn_s_setprio(1);                                         \
  MMAQ(1, 1);                                                            \
  MMAQ(1, 0);                                                            \
  __builtin_amdgcn_s_setprio(0);                                         \
  asm volatile("s_waitcnt vmcnt(8)" ::: "memory");                       \
  __builtin_amdgcn_sched_barrier(0);                                     \
  __builtin_amdgcn_s_barrier(); /* b1: other buf's stage visible */

__global__ __launch_bounds__(512, 2) void gemm256(const _Float16* __restrict__ Ah,
                                                  const _Float16* __restrict__ WT,
                                                  float* __restrict__ C) {
  __shared__ __align__(16) _Float16 As[2][2][128 * 64];  // [buf][half][r][k]
  __shared__ __align__(16) _Float16 Bs[2][2][128 * 64];

  const int tid = threadIdx.x;
  const int lane = tid & 63;
  const int wid = tid >> 6;

  // bijective XCD swizzle (nwg=256 % 8 == 0); m fast-varying
  const int nwg = (int)gridDim.x;
  const int bid0 = (int)blockIdx.x;
  const int wg = (bid0 & 7) * (nwg >> 3) + (bid0 >> 3);
  const int m0 = (wg & 15) * 256;
  const int n0 = (wg >> 4) * 256;

  // staging: wave stages 8 rows/pass, 2 passes per half-tile; source pre-swizzled
  const int st_row = wid * 8 + (lane >> 3);
  const int st_k = ((lane & 7) ^ (lane >> 3)) * 8;
  size_t a_srow[2], b_srow[2];
#pragma unroll
  for (int h = 0; h < 2; ++h) {
    a_srow[h] = (size_t)(m0 + h * 128 + st_row) * KK + st_k;
    b_srow[h] = (size_t)(n0 + h * 128 + st_row) * KK + st_k;
  }

  // compute-side fragment addressing (16x16x32); asm base addresses
  const int wm = wid >> 2, wn = wid & 3;
  const int lr = lane & 15, lg = lane >> 4;
  int koffx[2];
#pragma unroll
  for (int ks = 0; ks < 2; ++ks)
    koffx[ks] = ((ks * 32 + lg * 8) * 2) ^ ((lr & 7) << 4);

  const unsigned asBase =
      (unsigned)(size_t)(__attribute__((address_space(3))) _Float16*)&As[0][0][0];
  const unsigned bsBase =
      (unsigned)(size_t)(__attribute__((address_space(3))) _Float16*)&Bs[0][0][0];
  const unsigned aAddr0 = asBase + wm * 8192 + lr * 128 + koffx[0];
  const unsigned aAddr1 = asBase + wm * 8192 + lr * 128 + koffx[1];
  const unsigned bAddr0 = bsBase + wn * 4096 + lr * 128 + koffx[0];
  const unsigned bAddr1 = bsBase + wn * 4096 + lr * 128 + koffx[1];

  f32x4 acc[2][4][2][2];
#pragma unroll
  for (int h = 0; h < 2; ++h)
#pragma unroll
    for (int f = 0; f < 4; ++f)
#pragma unroll
      for (int g = 0; g < 2; ++g)
#pragma unroll
        for (int e = 0; e < 2; ++e) acc[h][f][g][e] = (f32x4){0.f, 0.f, 0.f, 0.f};

  f16x8 aF[2][2][4];  // [h][ks][f] — both halves retained across the K-tile
  f16x8 bF[2][2][2];  // [g][ks][e]

  // ---- prologue: stage tile 0 -> buf0 (8 loads), tile 1 -> buf1 (8 loads) ----
  STAGE_A(0, 0, 0);
  STAGE_A(0, 1, 0);
  STAGE_B(0, 0, 0);
  STAGE_B(0, 1, 0);
  STAGE_A(1, 0, 1);
  STAGE_A(1, 1, 1);
  STAGE_B(1, 0, 1);
  STAGE_B(1, 1, 1);
  asm volatile("s_waitcnt vmcnt(8)" ::: "memory");
  __builtin_amdgcn_sched_barrier(0);
  __builtin_amdgcn_s_barrier();

  // ---- main loop: 2 K-tiles per iteration, 2 mega-phases ----
  for (int i = 0; i < NT / 2; ++i) {
    const int t2 = (2 * i + 2) & (NT - 1);  // wrap on last iter (harmless restage)
    const int t3 = (2 * i + 3) & (NT - 1);
    MEGA(0, t2);
    MEGA(1, t3);
  }

  // ---- epilogue: C/D col=lane&15, row=(lane>>4)*4+reg ----
#pragma unroll
  for (int h = 0; h < 2; ++h)
#pragma unroll
    for (int f = 0; f < 4; ++f) {
      const int row0 = m0 + h * 128 + wm * 64 + f * 16 + lg * 4;
#pragma unroll
      for (int g = 0; g < 2; ++g)
#pragma unroll
        for (int e = 0; e < 2; ++e) {
          const int col = n0 + g * 128 + wn * 32 + e * 16 + lr;
#pragma unroll
          for (int r = 0; r < 4; ++r)
            C[(size_t)(row0 + r) * NN + col] = acc[h][f][g][e][r];
        }
    }
}

// ================= fallback: Round-5 fused kernel (proven) =================
__global__ __launch_bounds__(256, 2) void wq_gemm(
    const float* __restrict__ A, const int* __restrict__ Q,
    const float* __restrict__ S, const float* __restrict__ Z,
    float* __restrict__ C) {
  __shared__ __align__(16) _Float16 AsBuf[2][128 * 64];
  __shared__ __align__(16) _Float16 BsBuf[2][128 * 64];

  const int tid = threadIdx.x;
  const int lane = tid & 63;
  const int wid = tid >> 6;

  const int nwg = (int)gridDim.x;
  const int bid0 = (int)blockIdx.x;
  const int wg = (bid0 & 7) * (nwg >> 3) + (bid0 >> 3);
  const int m0 = (wg & 31) * 128;
  const int n0 = (wg >> 5) * 128;

  const int a_m = tid >> 3;
  const int a_k = (tid & 7) * 8;
  const float* a_src = A + (size_t)(m0 + a_m) * KK + a_k;
  const int a_woff = a_m * 128 + ((a_k * 2) ^ ((a_m & 7) << 4));

  const int n_loc = tid & 127;
  const int kk0 = (tid >> 7) * 32;
  const int* q_src = Q + (size_t)kk0 * NN + (n0 + n_loc);
  const float* s_src = S + (n0 + n_loc);
  const float* z_src = Z + (n0 + n_loc);
  int bw_off[4];
#pragma unroll
  for (int j = 0; j < 4; ++j)
    bw_off[j] = n_loc * 128 + (((kk0 + j * 8) * 2) ^ ((n_loc & 7) << 4));

  const int wm = wid >> 1, wn = wid & 1;
  const int lr = lane & 15, lg = lane >> 4;
  const int rx = (lr & 7) << 4;
  int a_row[4], b_row[4], koffx[2];
#pragma unroll
  for (int f = 0; f < 4; ++f) {
    a_row[f] = (wm * 64 + f * 16 + lr) * 128;
    b_row[f] = (wn * 64 + f * 16 + lr) * 128;
  }
#pragma unroll
  for (int ks = 0; ks < 2; ++ks)
    koffx[ks] = ((ks * 32 + lg * 8) * 2) ^ rx;

  f32x4 acc[4][4];
#pragma unroll
  for (int i = 0; i < 4; ++i)
#pragma unroll
    for (int j = 0; j < 4; ++j) acc[i][j] = (f32x4){0.f, 0.f, 0.f, 0.f};

  f32x4 av[8];
  int qv[32];
  float sf, bfv;

  auto stage_load = [&](int t) {
    const float* ap = a_src + (size_t)t * 64;
#pragma unroll
    for (int p = 0; p < 4; ++p) {
      av[p * 2] = *(const f32x4*)(ap + (size_t)p * 32 * KK);
      av[p * 2 + 1] = *(const f32x4*)(ap + (size_t)p * 32 * KK + 4);
    }
    const int* qp = q_src + (size_t)t * 64 * NN;
#pragma unroll
    for (int i = 0; i < 32; ++i) qv[i] = qp[(size_t)i * NN];
    const int g = t >> 1;
    sf = s_src[(size_t)g * NN];
    bfv = -z_src[(size_t)g * NN] * sf;
  };

  auto stage_write = [&](int c) {
    char* as = (char*)&AsBuf[c][0];
#pragma unroll
    for (int p = 0; p < 4; ++p) {
      union { f16x2 h2[4]; f16x8 v; } u;
      f32x4 v0 = av[p * 2], v1 = av[p * 2 + 1];
      u.h2[0] = pk16(v0[0], v0[1]);
      u.h2[1] = pk16(v0[2], v0[3]);
      u.h2[2] = pk16(v1[0], v1[1]);
      u.h2[3] = pk16(v1[2], v1[3]);
      *(f16x8*)(as + a_woff + p * 4096) = u.v;
    }
    char* bs = (char*)&BsBuf[c][0];
#pragma unroll
    for (int j = 0; j < 4; ++j) {
      union { f16x2 h2[4]; f16x8 v; } u;
#pragma unroll
      for (int p = 0; p < 4; ++p) {
        float w0 = (float)qv[j * 8 + p * 2] * sf + bfv;
        float w1 = (float)qv[j * 8 + p * 2 + 1] * sf + bfv;
        u.h2[p] = pk16(w0, w1);
      }
      *(f16x8*)(bs + bw_off[j]) = u.v;
    }
  };

  stage_load(0);
  stage_write(0);
  __syncthreads();

  for (int t = 0; t < NT; ++t) {
    const int c = t & 1;
    if (t + 1 < NT) stage_load(t + 1);
    {
      const char* as = (const char*)&AsBuf[c][0];
      const char* bs = (const char*)&BsBuf[c][0];
#pragma unroll
      for (int ks = 0; ks < 2; ++ks) {
        f16x8 a4[4], b4[4];
#pragma unroll
        for (int f = 0; f < 4; ++f) {
          a4[f] = *(const f16x8*)(as + (a_row[f] + koffx[ks]));
          b4[f] = *(const f16x8*)(bs + (b_row[f] + koffx[ks]));
        }
#pragma unroll
        for (int i = 0; i < 4; ++i)
#pragma unroll
          for (int j = 0; j < 4; ++j)
            acc[i][j] = __builtin_amdgcn_mfma_f32_16x16x32_f16(
                a4[i], b4[j], acc[i][j], 0, 0, 0);
      }
    }
    if (t + 1 < NT) stage_write(c ^ 1);
    __syncthreads();
  }

#pragma unroll
  for (int i = 0; i < 4; ++i) {
    const int row0 = m0 + wm * 64 + i * 16 + lg * 4;
#pragma unroll
    for (int j = 0; j < 4; ++j) {
      const int col = n0 + wn * 64 + j * 16 + lr;
#pragma unroll
      for (int r = 0; r < 4; ++r)
        C[(size_t)(row0 + r) * NN + col] = acc[i][j][r];
    }
  }
}

extern "C" void kernel_launch(void* const* d_in, const int* in_sizes, int n_in,
                              void* d_out, int out_size, void* d_ws, size_t ws_size,
                              hipStream_t stream) {
  const float* A = (const float*)d_in[0];
  const int* Q = (const int*)d_in[1];
  const float* S = (const float*)d_in[2];
  const float* Z = (const float*)d_in[3];
  float* C = (float*)d_out;

  const size_t needA = (size_t)MM * KK * sizeof(_Float16);
  const size_t needW = (size_t)KK * NN * sizeof(_Float16);
  if (ws_size >= needA + needW) {
    _Float16* Ah = (_Float16*)d_ws;
    _Float16* WT = (_Float16*)((char*)d_ws + needA);
    prep<<<dim3(8192 + 4096), dim3(256), 0, stream>>>(A, Ah, Q, S, Z, WT);
    gemm256<<<dim3((MM / 256) * (NN / 256)), dim3(512), 0, stream>>>(Ah, WT, C);
  } else {
    wq_gemm<<<dim3((MM / 128) * (NN / 128)), dim3(256), 0, stream>>>(A, Q, S, Z, C);
  }
}

// Round 21
// 150.933 us; speedup vs baseline: 1.9305x; 1.0232x over previous
//
#include <hip/hip_runtime.h>

#define MM 4096
#define NN 4096
#define KK 4096
#define NT (KK / 64)

typedef __attribute__((ext_vector_type(8))) _Float16 f16x8;
typedef __attribute__((ext_vector_type(2))) _Float16 f16x2;
typedef __attribute__((ext_vector_type(4))) float f32x4;
typedef __attribute__((ext_vector_type(4))) int i32x4;

__device__ __forceinline__ f16x2 pk16(float a, float b) {
  return __builtin_bit_cast(f16x2, __builtin_amdgcn_cvt_pkrtz(a, b));
}

__device__ __forceinline__ void gload_lds16(const void* g, void* l) {
  __builtin_amdgcn_global_load_lds(
      (const __attribute__((address_space(1))) unsigned int*)g,
      (__attribute__((address_space(3))) unsigned int*)l, 16, 0, 0);
}

// ================= pre-pass 1: A fp32 -> fp16 =================
__global__ __launch_bounds__(256) void cvt_a(const float* __restrict__ A,
                                             _Float16* __restrict__ Ah) {
  const size_t i = ((size_t)blockIdx.x * 256 + threadIdx.x) * 8;
  f32x4 v0 = *(const f32x4*)(A + i);
  f32x4 v1 = *(const f32x4*)(A + i + 4);
  union { f16x2 h2[4]; f16x8 v; } u;
  u.h2[0] = pk16(v0[0], v0[1]);
  u.h2[1] = pk16(v0[2], v0[3]);
  u.h2[2] = pk16(v1[0], v1[1]);
  u.h2[3] = pk16(v1[2], v1[3]);
  *(f16x8*)(Ah + i) = u.v;
}

// ====== pre-pass 2: dequant Q[k][n] -> W^T[n][k] fp16 (64x64 LDS transpose) ======
__global__ __launch_bounds__(256) void deq_wt(const int* __restrict__ Q,
                                              const float* __restrict__ S,
                                              const float* __restrict__ Z,
                                              _Float16* __restrict__ WT) {
  __shared__ _Float16 T[64][72];
  const int tid = threadIdx.x;
  const int n0 = ((int)blockIdx.x & 63) * 64;
  const int k0 = ((int)blockIdx.x >> 6) * 64;
  const int g = k0 >> 7;

  const int c4 = (tid & 15) * 4;
  f32x4 s4 = *(const f32x4*)(S + (size_t)g * NN + n0 + c4);
  f32x4 z4 = *(const f32x4*)(Z + (size_t)g * NN + n0 + c4);
#pragma unroll
  for (int p = 0; p < 4; ++p) {
    const int r = (tid >> 4) + p * 16;
    i32x4 q = *(const i32x4*)(Q + (size_t)(k0 + r) * NN + n0 + c4);
#pragma unroll
    for (int j = 0; j < 4; ++j)
      T[c4 + j][r] = (_Float16)(((float)q[j] - z4[j]) * s4[j]);
  }
  __syncthreads();
  const int n = tid >> 2;
  const int kc = (tid & 3) * 16;
  f16x8 w0 = *(const f16x8*)&T[n][kc];
  f16x8 w1 = *(const f16x8*)&T[n][kc + 8];
  _Float16* dst = WT + (size_t)(n0 + n) * KK + k0 + kc;
  *(f16x8*)dst = w0;
  *(f16x8*)(dst + 8) = w1;
}

// ==== main GEMM: 256x256, 8 waves, SINGLE-BARRIER K-tile mega-phase ====
// R17 minus the mid-tile b2: true double-buffer restored. Tile t consumes
// buf c=t&1; stage of buf c^1 <- tile t+1 issued at TOP of tile t (c^1's
// last reads completed at tile t-1's lgkm(0), which precedes tile t-1's
// end barrier -> restage is >=1 barrier after last read). vmcnt(0) at tail
// drains this tile's 16 stages with ~full-tile slack (nearly free).
// Counted lgkm waits gain issue-to-wait distance (16 VMEM issues precede).

#define DSR(DST, ADDR, IMM)                                              \
  asm volatile("ds_read_b128 %0, %1 offset:%2"                           \
               : "=v"(DST) : "v"(ADDR), "i"(IMM))

#define OFFA(BUF, H, F) (((BUF) * 2 + (H)) * 16384 + (F) * 2048)
#define OFFB(BUF, G, E) (((BUF) * 2 + (G)) * 16384 + (E) * 2048)

#define READ_ASET(BUF, H)                                                \
  DSR(aF[H][0][0], aAddr0, OFFA(BUF, H, 0));                             \
  DSR(aF[H][0][1], aAddr0, OFFA(BUF, H, 1));                             \
  DSR(aF[H][0][2], aAddr0, OFFA(BUF, H, 2));                             \
  DSR(aF[H][0][3], aAddr0, OFFA(BUF, H, 3));                             \
  DSR(aF[H][1][0], aAddr1, OFFA(BUF, H, 0));                             \
  DSR(aF[H][1][1], aAddr1, OFFA(BUF, H, 1));                             \
  DSR(aF[H][1][2], aAddr1, OFFA(BUF, H, 2));                             \
  DSR(aF[H][1][3], aAddr1, OFFA(BUF, H, 3))

#define READ_BSET(BUF, G)                                                \
  DSR(bF[G][0][0], bAddr0, OFFB(BUF, G, 0));                             \
  DSR(bF[G][0][1], bAddr0, OFFB(BUF, G, 1));                             \
  DSR(bF[G][1][0], bAddr1, OFFB(BUF, G, 0));                             \
  DSR(bF[G][1][1], bAddr1, OFFB(BUF, G, 1))

#define STAGE_A(BUF, H, T)                                               \
  { const _Float16* src_ = Ah + a_srow[H] + (size_t)(T) * 64;            \
    char* dst_ = (char*)&As[BUF][H][0] + wid * 1024;                     \
    gload_lds16(src_, dst_);                                             \
    gload_lds16(src_ + (size_t)64 * KK, dst_ + 8192); }

#define STAGE_B(BUF, G, T)                                               \
  { const _Float16* src_ = WT + b_srow[G] + (size_t)(T) * 64;            \
    char* dst_ = (char*)&Bs[BUF][G][0] + wid * 1024;                     \
    gload_lds16(src_, dst_);                                             \
    gload_lds16(src_ + (size_t)64 * KK, dst_ + 8192); }

#define MMAQ(H, G)                                                       \
  _Pragma("unroll") for (int ks = 0; ks < 2; ++ks)                       \
  _Pragma("unroll") for (int f = 0; f < 4; ++f)                          \
  _Pragma("unroll") for (int e = 0; e < 2; ++e)                          \
    acc[H][f][G][e] = __builtin_amdgcn_mfma_f32_16x16x32_f16(            \
        aF[H][ks][f], bF[G][ks][e], acc[H][f][G][e], 0, 0, 0);

// Single-barrier K-tile: stage buf^1<-TN at top; reads+counted waits+MFMA;
// tail vmcnt(0) (full-tile slack) + ONE barrier.
#define MEGA(BUF, TN)                                                    \
  STAGE_A((BUF) ^ 1, 0, TN);                                             \
  STAGE_A((BUF) ^ 1, 1, TN);                                             \
  STAGE_B((BUF) ^ 1, 0, TN);                                             \
  STAGE_B((BUF) ^ 1, 1, TN);                                             \
  READ_ASET(BUF, 0);                                                     \
  READ_BSET(BUF, 0);                                                     \
  READ_BSET(BUF, 1);                                                     \
  READ_ASET(BUF, 1);                                                     \
  asm volatile("s_waitcnt lgkmcnt(12)" ::: "memory");                    \
  __builtin_amdgcn_sched_barrier(0);                                     \
  __builtin_amdgcn_s_setprio(1);                                         \
  MMAQ(0, 0);                                                            \
  __builtin_amdgcn_s_setprio(0);                                         \
  asm volatile("s_waitcnt lgkmcnt(8)" ::: "memory");                     \
  __builtin_amdgcn_sched_barrier(0);                                     \
  __builtin_amdgcn_s_setprio(1);                                         \
  MMAQ(0, 1);                                                            \
  __builtin_amdgcn_s_setprio(0);                                         \
  asm volatile("s_waitcnt lgkmcnt(0)" ::: "memory");                     \
  __builtin_amdgcn_sched_barrier(0);                                     \
  __builtin_amdgcn_s_setprio(1);                                         \
  MMAQ(1, 1);                                                            \
  MMAQ(1, 0);                                                            \
  __builtin_amdgcn_s_setprio(0);                                         \
  asm volatile("s_waitcnt vmcnt(0)" ::: "memory");                       \
  __builtin_amdgcn_sched_barrier(0);                                     \
  __builtin_amdgcn_s_barrier(); /* publishes buf^1 for tile t+1 */

__global__ __launch_bounds__(512, 2) void gemm256(const _Float16* __restrict__ Ah,
                                                  const _Float16* __restrict__ WT,
                                                  float* __restrict__ C) {
  __shared__ __align__(16) _Float16 As[2][2][128 * 64];  // [buf][half][r][k]
  __shared__ __align__(16) _Float16 Bs[2][2][128 * 64];

  const int tid = threadIdx.x;
  const int lane = tid & 63;
  const int wid = tid >> 6;

  // bijective XCD swizzle (nwg=256 % 8 == 0); m fast-varying
  const int nwg = (int)gridDim.x;
  const int bid0 = (int)blockIdx.x;
  const int wg = (bid0 & 7) * (nwg >> 3) + (bid0 >> 3);
  const int m0 = (wg & 15) * 256;
  const int n0 = (wg >> 4) * 256;

  // staging: wave stages 8 rows/pass, 2 passes per half-tile; source pre-swizzled
  const int st_row = wid * 8 + (lane >> 3);
  const int st_k = ((lane & 7) ^ (lane >> 3)) * 8;
  size_t a_srow[2], b_srow[2];
#pragma unroll
  for (int h = 0; h < 2; ++h) {
    a_srow[h] = (size_t)(m0 + h * 128 + st_row) * KK + st_k;
    b_srow[h] = (size_t)(n0 + h * 128 + st_row) * KK + st_k;
  }

  // compute-side fragment addressing (16x16x32); asm base addresses
  const int wm = wid >> 2, wn = wid & 3;
  const int lr = lane & 15, lg = lane >> 4;
  int koffx[2];
#pragma unroll
  for (int ks = 0; ks < 2; ++ks)
    koffx[ks] = ((ks * 32 + lg * 8) * 2) ^ ((lr & 7) << 4);

  const unsigned asBase =
      (unsigned)(size_t)(__attribute__((address_space(3))) _Float16*)&As[0][0][0];
  const unsigned bsBase =
      (unsigned)(size_t)(__attribute__((address_space(3))) _Float16*)&Bs[0][0][0];
  const unsigned aAddr0 = asBase + wm * 8192 + lr * 128 + koffx[0];
  const unsigned aAddr1 = asBase + wm * 8192 + lr * 128 + koffx[1];
  const unsigned bAddr0 = bsBase + wn * 4096 + lr * 128 + koffx[0];
  const unsigned bAddr1 = bsBase + wn * 4096 + lr * 128 + koffx[1];

  f32x4 acc[2][4][2][2];
#pragma unroll
  for (int h = 0; h < 2; ++h)
#pragma unroll
    for (int f = 0; f < 4; ++f)
#pragma unroll
      for (int g = 0; g < 2; ++g)
#pragma unroll
        for (int e = 0; e < 2; ++e) acc[h][f][g][e] = (f32x4){0.f, 0.f, 0.f, 0.f};

  f16x8 aF[2][2][4];  // [h][ks][f]
  f16x8 bF[2][2][2];  // [g][ks][e]

  // ---- prologue: stage tile 0 -> buf0 only (tile 1 staged inside MEGA(0,1)) ----
  STAGE_A(0, 0, 0);
  STAGE_A(0, 1, 0);
  STAGE_B(0, 0, 0);
  STAGE_B(0, 1, 0);
  asm volatile("s_waitcnt vmcnt(0)" ::: "memory");
  __builtin_amdgcn_sched_barrier(0);
  __builtin_amdgcn_s_barrier();

  // ---- main loop: one single-barrier mega-phase per K-tile ----
  for (int i = 0; i < NT / 2; ++i) {
    const int t1 = 2 * i + 1;
    const int t2 = (2 * i + 2) & (NT - 1);  // wrap on last iter (harmless restage)
    MEGA(0, t1);
    MEGA(1, t2);
  }

  // ---- epilogue: C/D col=lane&15, row=(lane>>4)*4+reg ----
#pragma unroll
  for (int h = 0; h < 2; ++h)
#pragma unroll
    for (int f = 0; f < 4; ++f) {
      const int row0 = m0 + h * 128 + wm * 64 + f * 16 + lg * 4;
#pragma unroll
      for (int g = 0; g < 2; ++g)
#pragma unroll
        for (int e = 0; e < 2; ++e) {
          const int col = n0 + g * 128 + wn * 32 + e * 16 + lr;
#pragma unroll
          for (int r = 0; r < 4; ++r)
            C[(size_t)(row0 + r) * NN + col] = acc[h][f][g][e][r];
        }
    }
}

// ================= fallback: Round-5 fused kernel (proven) =================
__global__ __launch_bounds__(256, 2) void wq_gemm(
    const float* __restrict__ A, const int* __restrict__ Q,
    const float* __restrict__ S, const float* __restrict__ Z,
    float* __restrict__ C) {
  __shared__ __align__(16) _Float16 AsBuf[2][128 * 64];
  __shared__ __align__(16) _Float16 BsBuf[2][128 * 64];

  const int tid = threadIdx.x;
  const int lane = tid & 63;
  const int wid = tid >> 6;

  const int nwg = (int)gridDim.x;
  const int bid0 = (int)blockIdx.x;
  const int wg = (bid0 & 7) * (nwg >> 3) + (bid0 >> 3);
  const int m0 = (wg & 31) * 128;
  const int n0 = (wg >> 5) * 128;

  const int a_m = tid >> 3;
  const int a_k = (tid & 7) * 8;
  const float* a_src = A + (size_t)(m0 + a_m) * KK + a_k;
  const int a_woff = a_m * 128 + ((a_k * 2) ^ ((a_m & 7) << 4));

  const int n_loc = tid & 127;
  const int kk0 = (tid >> 7) * 32;
  const int* q_src = Q + (size_t)kk0 * NN + (n0 + n_loc);
  const float* s_src = S + (n0 + n_loc);
  const float* z_src = Z + (n0 + n_loc);
  int bw_off[4];
#pragma unroll
  for (int j = 0; j < 4; ++j)
    bw_off[j] = n_loc * 128 + (((kk0 + j * 8) * 2) ^ ((n_loc & 7) << 4));

  const int wm = wid >> 1, wn = wid & 1;
  const int lr = lane & 15, lg = lane >> 4;
  const int rx = (lr & 7) << 4;
  int a_row[4], b_row[4], koffx[2];
#pragma unroll
  for (int f = 0; f < 4; ++f) {
    a_row[f] = (wm * 64 + f * 16 + lr) * 128;
    b_row[f] = (wn * 64 + f * 16 + lr) * 128;
  }
#pragma unroll
  for (int ks = 0; ks < 2; ++ks)
    koffx[ks] = ((ks * 32 + lg * 8) * 2) ^ rx;

  f32x4 acc[4][4];
#pragma unroll
  for (int i = 0; i < 4; ++i)
#pragma unroll
    for (int j = 0; j < 4; ++j) acc[i][j] = (f32x4){0.f, 0.f, 0.f, 0.f};

  f32x4 av[8];
  int qv[32];
  float sf, bfv;

  auto stage_load = [&](int t) {
    const float* ap = a_src + (size_t)t * 64;
#pragma unroll
    for (int p = 0; p < 4; ++p) {
      av[p * 2] = *(const f32x4*)(ap + (size_t)p * 32 * KK);
      av[p * 2 + 1] = *(const f32x4*)(ap + (size_t)p * 32 * KK + 4);
    }
    const int* qp = q_src + (size_t)t * 64 * NN;
#pragma unroll
    for (int i = 0; i < 32; ++i) qv[i] = qp[(size_t)i * NN];
    const int g = t >> 1;
    sf = s_src[(size_t)g * NN];
    bfv = -z_src[(size_t)g * NN] * sf;
  };

  auto stage_write = [&](int c) {
    char* as = (char*)&AsBuf[c][0];
#pragma unroll
    for (int p = 0; p < 4; ++p) {
      union { f16x2 h2[4]; f16x8 v; } u;
      f32x4 v0 = av[p * 2], v1 = av[p * 2 + 1];
      u.h2[0] = pk16(v0[0], v0[1]);
      u.h2[1] = pk16(v0[2], v0[3]);
      u.h2[2] = pk16(v1[0], v1[1]);
      u.h2[3] = pk16(v1[2], v1[3]);
      *(f16x8*)(as + a_woff + p * 4096) = u.v;
    }
    char* bs = (char*)&BsBuf[c][0];
#pragma unroll
    for (int j = 0; j < 4; ++j) {
      union { f16x2 h2[4]; f16x8 v; } u;
#pragma unroll
      for (int p = 0; p < 4; ++p) {
        float w0 = (float)qv[j * 8 + p * 2] * sf + bfv;
        float w1 = (float)qv[j * 8 + p * 2 + 1] * sf + bfv;
        u.h2[p] = pk16(w0, w1);
      }
      *(f16x8*)(bs + bw_off[j]) = u.v;
    }
  };

  stage_load(0);
  stage_write(0);
  __syncthreads();

  for (int t = 0; t < NT; ++t) {
    const int c = t & 1;
    if (t + 1 < NT) stage_load(t + 1);
    {
      const char* as = (const char*)&AsBuf[c][0];
      const char* bs = (const char*)&BsBuf[c][0];
#pragma unroll
      for (int ks = 0; ks < 2; ++ks) {
        f16x8 a4[4], b4[4];
#pragma unroll
        for (int f = 0; f < 4; ++f) {
          a4[f] = *(const f16x8*)(as + (a_row[f] + koffx[ks]));
          b4[f] = *(const f16x8*)(bs + (b_row[f] + koffx[ks]));
        }
#pragma unroll
        for (int i = 0; i < 4; ++i)
#pragma unroll
          for (int j = 0; j < 4; ++j)
            acc[i][j] = __builtin_amdgcn_mfma_f32_16x16x32_f16(
                a4[i], b4[j], acc[i][j], 0, 0, 0);
      }
    }
    if (t + 1 < NT) stage_write(c ^ 1);
    __syncthreads();
  }

#pragma unroll
  for (int i = 0; i < 4; ++i) {
    const int row0 = m0 + wm * 64 + i * 16 + lg * 4;
#pragma unroll
    for (int j = 0; j < 4; ++j) {
      const int col = n0 + wn * 64 + j * 16 + lr;
#pragma unroll
      for (int r = 0; r < 4; ++r)
        C[(size_t)(row0 + r) * NN + col] = acc[i][j][r];
    }
  }
}

extern "C" void kernel_launch(void* const* d_in, const int* in_sizes, int n_in,
                              void* d_out, int out_size, void* d_ws, size_t ws_size,
                              hipStream_t stream) {
  const float* A = (const float*)d_in[0];
  const int* Q = (const int*)d_in[1];
  const float* S = (const float*)d_in[2];
  const float* Z = (const float*)d_in[3];
  float* C = (float*)d_out;

  const size_t needA = (size_t)MM * KK * sizeof(_Float16);
  const size_t needW = (size_t)KK * NN * sizeof(_Float16);
  if (ws_size >= needA + needW) {
    _Float16* Ah = (_Float16*)d_ws;
    _Float16* WT = (_Float16*)((char*)d_ws + needA);
    cvt_a<<<dim3(MM * KK / (8 * 256)), dim3(256), 0, stream>>>(A, Ah);
    deq_wt<<<dim3((KK / 64) * (NN / 64)), dim3(256), 0, stream>>>(Q, S, Z, WT);
    gemm256<<<dim3((MM / 256) * (NN / 256)), dim3(512), 0, stream>>>(Ah, WT, C);
  } else {
    wq_gemm<<<dim3((MM / 128) * (NN / 128)), dim3(256), 0, stream>>>(A, Q, S, Z, C);
  }
}